// Round 7
// baseline (1486.113 us; speedup 1.0000x reference)
//
#include <hip/hip_runtime.h>
#include <hip/hip_bf16.h>

#define NH_K 16
#define NH_V 32
#define D_K 128
#define D_V 128
#define QKVZ_COLS 12288

typedef __attribute__((ext_vector_type(8))) __bf16 bf16x8;
typedef __attribute__((ext_vector_type(4))) __bf16 bf16x4;
typedef __attribute__((ext_vector_type(2))) __bf16 bf16x2;
typedef __attribute__((ext_vector_type(4))) float floatx4;
typedef __attribute__((ext_vector_type(4))) unsigned int uint32x4;

// global_load_lds: LDS dest = wave-uniform base + lane*16; global src per-lane.
#define GLDS16(gp, lp) __builtin_amdgcn_global_load_lds( \
    (const __attribute__((address_space(1))) unsigned int*)(gp), \
    (__attribute__((address_space(3))) unsigned int*)(lp), 16, 0, 0)

__device__ __forceinline__ float sigm(float x) {
  float e = expf(-fabsf(x));
  return (x >= 0.f) ? 1.f / (1.f + e) : e / (1.f + e);
}
__device__ __forceinline__ float clampf(float v, float m) {
  return fminf(fmaxf(v, -m), m);      // scrubs NaN too
}
// dtype-flexible scalar load: flag chooses fp32 vs bf16 interpretation
__device__ __forceinline__ float loadF(const void* p, size_t i, bool f32) {
  return f32 ? ((const float*)p)[i] : (float)((const __bf16*)p)[i];
}

// ---------------------------------------------------------------------------
// Input dtype sniffer (validated: flags fp32 correctly). bits 7..14 of
// each word = bf16 exponent field (always in [100,135] for N(0,1) bf16 pairs)
// vs fp32 mantissa bits (uniform, ~14% in range).
// ---------------------------------------------------------------------------
__global__ __launch_bounds__(256) void detect_kernel(
    const unsigned int* __restrict__ x, int* __restrict__ flag)
{
  __shared__ int cnt;
  if (threadIdx.x == 0) cnt = 0;
  __syncthreads();
  unsigned int w = x[threadIdx.x];
  int e = (w >> 7) & 0xFF;
  if (e >= 100 && e <= 135) atomicAdd(&cnt, 1);
  __syncthreads();
  if (threadIdx.x == 0) *flag = (cnt < 128) ? 1 : 0;   // 1 = fp32 inputs
}

// ---------------------------------------------------------------------------
// x (fp32 or bf16) -> xb (bf16), 8 elems/thread, fully coalesced.
// ---------------------------------------------------------------------------
__global__ __launch_bounds__(256) void convx_kernel(
    const void* __restrict__ x, __bf16* __restrict__ xb,
    const int* __restrict__ flagp)
{
  const bool f32 = (*flagp != 0);
  size_t i = ((size_t)blockIdx.x * 256 + threadIdx.x) * 8;
  if (f32) {
    float4 a = *(const float4*)&((const float*)x)[i];
    float4 b = *(const float4*)&((const float*)x)[i + 4];
    bf16x8 v;
    v[0]=(__bf16)a.x; v[1]=(__bf16)a.y; v[2]=(__bf16)a.z; v[3]=(__bf16)a.w;
    v[4]=(__bf16)b.x; v[5]=(__bf16)b.y; v[6]=(__bf16)b.z; v[7]=(__bf16)b.w;
    *(bf16x8*)&xb[i] = v;
  } else {
    *(uint32x4*)&xb[i] = *(const uint32x4*)&((const __bf16*)x)[i];
  }
}

// ---------------------------------------------------------------------------
// Transpose+convert: W[K][N] (fp32 or bf16) -> WT[N][K] bf16. 32x32 LDS tile.
// ---------------------------------------------------------------------------
__global__ __launch_bounds__(256) void trans_kernel(
    const void* __restrict__ W, __bf16* __restrict__ WT,
    int K, int N, const int* __restrict__ flagp)
{
  const bool f32 = (*flagp != 0);
  __shared__ float t[32][33];
  const int k0 = blockIdx.x * 32, n0 = blockIdx.y * 32;
  const int tid = threadIdx.x;
  {
    int r = tid >> 3, c4 = (tid & 7) * 4;
    if (f32) {
      float4 v = *(const float4*)&((const float*)W)[(size_t)(k0 + r) * N + n0 + c4];
      t[r][c4] = v.x; t[r][c4 + 1] = v.y; t[r][c4 + 2] = v.z; t[r][c4 + 3] = v.w;
    } else {
      bf16x4 v = *(const bf16x4*)&((const __bf16*)W)[(size_t)(k0 + r) * N + n0 + c4];
      t[r][c4] = (float)v[0]; t[r][c4 + 1] = (float)v[1];
      t[r][c4 + 2] = (float)v[2]; t[r][c4 + 3] = (float)v[3];
    }
  }
  __syncthreads();
  {
    int n = tid >> 3, k4 = (tid & 7) * 4;
    bf16x4 o;
#pragma unroll
    for (int j = 0; j < 4; ++j) o[j] = (__bf16)t[k4 + j][n];
    *(bf16x4*)&WT[(size_t)(n0 + n) * K + k0 + k4] = o;
  }
}

// ---------------------------------------------------------------------------
// 256x256 MFMA GEMM with counted-vmcnt double-buffer (T4) + st_16x32 LDS
// swizzle (T2). C = A @ BT^T; A[M][K], BT[N][K] bf16, K-contiguous.
// 512 threads = 8 waves (2 M-halves x 4 N-quarters); per-wave out 128x64.
// BK=32; LDS = 2 slots x (A 16KB + B 16KB) = 64 KB.
// Schedule per K-tile: {ds_read frags + 32 MFMA} ; s_barrier ;
//   stage kt+2 -> freed slot ; s_waitcnt vmcnt(4) (kt+1 landed, kt+2 in
//   flight — never drained to 0) ; s_barrier.  Raw barriers (not
//   __syncthreads) so the compiler's vmcnt(0) drain is avoided.
// Swizzle (rule #21): linear LDS dest (gload_lds) + inverse-swizzled global
//   source + swizzled ds_read.  swz(byte) = byte ^ (((byte>>9)&1)<<5).
// ---------------------------------------------------------------------------
template<bool OUT_F32>
__global__ __launch_bounds__(512, 1) void gemm_bt2(
    const __bf16* __restrict__ A, const __bf16* __restrict__ BT,
    void* __restrict__ C, int M, int N, int K)
{
  __shared__ __align__(16) __bf16 As[2][8192];   // [slot][256 rows x 32 cols]
  __shared__ __align__(16) __bf16 Bs[2][8192];
  const int tid = threadIdx.x;
  const int nx  = gridDim.x;
  const int nwg = nx * gridDim.y;
  int lid = blockIdx.y * nx + blockIdx.x;
  int swz = (lid & 7) * (nwg >> 3) + (lid >> 3);   // nwg % 8 == 0 (bijective)
  const int bn = (swz % nx) * 256;
  const int bm = (swz / nx) * 256;
  const int lane = tid & 63;
  const int wv   = tid >> 6;          // 0..7
  const int wm2  = wv >> 2;           // M-half (0..1)
  const int wn2  = wv & 3;            // N-quarter (0..3)
  const int l15  = lane & 15;
  const int quad = lane >> 4;
  const int NT   = K >> 5;

  // staging: thread covers LDS byte boff = L*8192 + wv*1024 + lane*16 within
  // a 16KB operand buffer; that physical slot holds logical swz(boff).
  auto stage = [&](int kt, int slot) {
    const int k0 = kt * 32;
#pragma unroll
    for (int L = 0; L < 2; ++L) {
      const int boff = L * 8192 + wv * 1024 + lane * 16;
      const int swb  = boff ^ (((boff >> 9) & 1) << 5);
      const int row  = swb >> 6;           // 64B per row
      const int ce   = (swb & 63) >> 1;    // col element
      GLDS16(&A[(size_t)(bm + row) * K + k0 + ce], &As[slot][L * 4096 + wv * 512]);
      GLDS16(&BT[(size_t)(bn + row) * K + k0 + ce], &Bs[slot][L * 4096 + wv * 512]);
    }
  };

  floatx4 acc[8][4];
#pragma unroll
  for (int a = 0; a < 8; ++a)
#pragma unroll
    for (int b = 0; b < 4; ++b)
      acc[a][b] = (floatx4){0.f, 0.f, 0.f, 0.f};

  // fragment read byte offsets (swizzled): logical (r, quad*8..+8) lives at
  // (r*64 + quad*16) ^ (((r>>3)&1)<<5); r>>3 bit == l15>>3 here.
  const int flip  = (l15 & 8) ? 32 : 0;
  const int baseA = (((wm2 * 128 + l15) * 64 + quad * 16) ^ flip);
  const int baseB = (((wn2 * 64 + l15) * 64 + quad * 16) ^ flip);

  // prologue: stage kt0 (slot0) + kt1 (slot1); wait kt0 only.
  stage(0, 0);
  stage(1, 1);
  asm volatile("s_waitcnt vmcnt(4)" ::: "memory");
  __builtin_amdgcn_s_barrier();
  __builtin_amdgcn_sched_barrier(0);

  for (int kt = 0; kt < NT; ++kt) {
    const int cur = kt & 1;
    const char* Ab = (const char*)&As[cur][0];
    const char* Bb = (const char*)&Bs[cur][0];
    bf16x8 af[8], bfr[4];
#pragma unroll
    for (int mt = 0; mt < 8; ++mt)
      af[mt] = *(const bf16x8*)(Ab + baseA + mt * 1024);
#pragma unroll
    for (int nt = 0; nt < 4; ++nt)
      bfr[nt] = *(const bf16x8*)(Bb + baseB + nt * 1024);
#pragma unroll
    for (int mt = 0; mt < 8; ++mt)
#pragma unroll
      for (int nt = 0; nt < 4; ++nt)
        acc[mt][nt] = __builtin_amdgcn_mfma_f32_16x16x32_bf16(af[mt], bfr[nt], acc[mt][nt], 0, 0, 0);
    if (kt + 1 < NT) {
      __builtin_amdgcn_s_barrier();               // all waves done reading cur
      if (kt + 2 < NT) {
        stage(kt + 2, cur);                       // refill freed slot
        asm volatile("s_waitcnt vmcnt(4)" ::: "memory");   // kt+1 landed
      } else {
        asm volatile("s_waitcnt vmcnt(0)" ::: "memory");
      }
      __builtin_amdgcn_s_barrier();               // kt+1 visible to all waves
      __builtin_amdgcn_sched_barrier(0);
    }
  }

#pragma unroll
  for (int mt = 0; mt < 8; ++mt)
#pragma unroll
    for (int nt = 0; nt < 4; ++nt)
#pragma unroll
      for (int r = 0; r < 4; ++r) {
        int row = bm + wm2 * 128 + mt * 16 + quad * 4 + r;  // C/D: row=quad*4+reg
        int col = bn + wn2 * 64 + nt * 16 + l15;
        if (OUT_F32) ((float*)C)[(size_t)row * N + col] = acc[mt][nt][r];
        else         ((__bf16*)C)[(size_t)row * N + col] = (__bf16)acc[mt][nt][r];
      }
}

// ---------------------------------------------------------------------------
__global__ __launch_bounds__(64) void ba_kernel(
    const void* __restrict__ x, const void* __restrict__ Wba,
    float* __restrict__ ba, const int* __restrict__ flagp)
{
  __shared__ float xr[2048];
  const bool f32 = (*flagp != 0);
  int t = blockIdx.x, tid = threadIdx.x;
  for (int i = tid; i < 2048; i += 64) xr[i] = loadF(x, (size_t)t * 2048 + i, f32);
  __syncthreads();
  float acc = 0.f;
  for (int k = 0; k < 2048; ++k) acc += xr[k] * loadF(Wba, (size_t)k * 64 + tid, f32);
  ba[(size_t)t * 64 + tid] = acc;
}

// ---------------------------------------------------------------------------
// Scrambled depthwise conv (torch cat->transpose->reshape), silu, l2norm q/k.
// block = (slot, 256-wide t-tile); coalesced window staging + shfl reduce.
// ---------------------------------------------------------------------------
__global__ __launch_bounds__(256) void conv_kernel(
    const __bf16* __restrict__ qkvz, const void* __restrict__ conv_w,
    __bf16* __restrict__ qn, __bf16* __restrict__ kn, __bf16* __restrict__ vv,
    const int* __restrict__ flagp)
{
  __shared__ __bf16 yin[128][266];    // window: i in [0,264) <-> s2 = t0-8+i
  const bool f32 = (*flagp != 0);
  const int slot = blockIdx.x;        // 0..63
  const int tb   = blockIdx.y;        // 0..15
  const int tid  = threadIdx.x;
  int kind, h_out, cbase;
  if (slot < 16)      { kind = 0; h_out = slot;      cbase = slot * 128; }
  else if (slot < 32) { kind = 1; h_out = slot - 16; cbase = 2048 + h_out * 128; }
  else                { kind = 2; h_out = slot - 32; cbase = 4096 + h_out * 128; }
  const int hc  = cbase >> 9;         // constant per slot (128-range never crosses 512)
  const int cl0 = cbase & 511;
  const int t0  = tb * 256;

  // ---- stage: chunk ch -> (d = ch/33, k = ch%33), 8 els at i = 8k ----
  for (int ch = tid; ch < 128 * 33; ch += 256) {
    int d = ch / 33, k = ch - d * 33;
    int s2 = t0 - 8 + k * 8;
    uint32x4 val;
    if (s2 < 0) {                     // conv left boundary (tb==0, k==0 only)
      val = (uint32x4){0u, 0u, 0u, 0u};
    } else {
      int p  = (cl0 + d) * 4096 + s2;
      int tp = p >> 9, ep = p & 511;
      val = *(const uint32x4*)&qkvz[(size_t)tp * QKVZ_COLS + hc * 768 + ep];
    }
    unsigned int* dst = (unsigned int*)&yin[d][k * 8];   // dword-aligned
    dst[0] = val[0]; dst[1] = val[1]; dst[2] = val[2]; dst[3] = val[3];
  }
  __syncthreads();

  const int wv   = tid >> 6;
  const int lane = tid & 63;
  float w0[4], w1[4];
#pragma unroll
  for (int j = 0; j < 4; ++j) {
    w0[j] = loadF(conv_w, (size_t)(cbase + lane) * 4 + j, f32);
    w1[j] = loadF(conv_w, (size_t)(cbase + lane + 64) * 4 + j, f32);
  }
  const int ltend = wv * 64 + 64;
  for (int lt = wv * 64; lt < ltend; ++lt) {
    int t = t0 + lt;
    float a0 = 0.f, a1 = 0.f;
#pragma unroll
    for (int j = 0; j < 4; ++j) {     // s2 = t-3+j  ->  i = lt+5+j
      a0 += w0[j] * (float)yin[lane][lt + 5 + j];
      a1 += w1[j] * (float)yin[lane + 64][lt + 5 + j];
    }
    float v0 = a0 * sigm(a0), v1 = a1 * sigm(a1);
    if (kind == 2) {
      vv[((size_t)t * NH_V + h_out) * D_V + lane]      = (__bf16)v0;
      vv[((size_t)t * NH_V + h_out) * D_V + lane + 64] = (__bf16)v1;
    } else {
      float ss = v0 * v0 + v1 * v1;
#pragma unroll
      for (int off = 32; off; off >>= 1) ss += __shfl_xor(ss, off, 64);
      float scl = rsqrtf(ss + 1e-6f);
      if (kind == 0) scl *= 0.08838834764831845f;   // DK^-0.5
      __bf16* dst = (kind == 0) ? qn : kn;
      dst[((size_t)t * NH_K + h_out) * D_K + lane]      = (__bf16)(v0 * scl);
      dst[((size_t)t * NH_K + h_out) * D_K + lane + 64] = (__bf16)(v1 * scl);
    }
  }
}

// ---------------------------------------------------------------------------
__global__ __launch_bounds__(64) void gb_kernel(
    const float* __restrict__ ba, const void* __restrict__ dt_bias,
    const void* __restrict__ A_log, float* __restrict__ gbuf,
    float* __restrict__ betabuf, const int* __restrict__ flagp)
{
  const bool f32 = (*flagp != 0);
  int t = blockIdx.x;
  int hv = threadIdx.x;
  if (hv >= 32) return;
  float bv = ba[t * 64 + (hv >> 1) * 4 + (hv & 1)];
  float av = ba[t * 64 + (hv >> 1) * 4 + 2 + (hv & 1)];
  float beta = sigm(bv);
  float xx = av + loadF(dt_bias, hv, f32);
  float sp = (xx > 15.f) ? xx : log1pf(expf(fminf(xx, 15.f)));
  float g = -expf(loadF(A_log, hv, f32)) * sp;
  gbuf[t * 32 + hv] = g;
  betabuf[t * 32 + hv] = beta;
}

// ---------------------------------------------------------------------------
// Per-(head,chunk): g cumsum, M (MFMA), Tinv (1-wave barrier-free subst,
// overlapped with attn MFMA on waves 1-3), u/w (MFMA, Tinv hi/lo).
// ---------------------------------------------------------------------------
__global__ __launch_bounds__(256) void prep_kernel(
    const __bf16* __restrict__ qn, const __bf16* __restrict__ kn, const __bf16* __restrict__ vv,
    const float* __restrict__ gbuf, const float* __restrict__ betabuf,
    float* __restrict__ gcs, __bf16* __restrict__ u, __bf16* __restrict__ w,
    __bf16* __restrict__ attn)
{
  __shared__ float MT[64][67];        // M then Tinv (fp32); stride 67 ~conflict-free
  __shared__ __bf16 vT[128][72];      // v^T [dv][t]
  __shared__ __bf16 kT[128][72];      // k^T [dk][t]
  __shared__ float gc[64], betas[64], scu[64], scw[64];
  const int bid = blockIdx.x;
  const int hv = bid >> 6, n = bid & 63;
  const int hk = hv >> 1;
  const int t0 = n * 64;
  const int tid = threadIdx.x;
  const int wv = tid >> 6, lane = tid & 63;
  const int l15 = lane & 15, quad = lane >> 4;

  // ---- stage v^T, k^T: lane owns t=lane, wave owns 32 of 128 d's ----
  {
    const __bf16* vrow = &vv[((size_t)(t0 + lane) * NH_V + hv) * D_V + wv * 32];
    const __bf16* krow = &kn[((size_t)(t0 + lane) * NH_K + hk) * D_K + wv * 32];
#pragma unroll
    for (int c2 = 0; c2 < 4; ++c2) {
      bf16x8 v8 = *(const bf16x8*)&vrow[c2 * 8];
      bf16x8 k8 = *(const bf16x8*)&krow[c2 * 8];
#pragma unroll
      for (int j = 0; j < 8; ++j) {
        vT[wv * 32 + c2 * 8 + j][lane] = v8[j];
        kT[wv * 32 + c2 * 8 + j][lane] = k8[j];
      }
    }
  }
  if (tid < 64) {
    gc[tid]    = gbuf[(t0 + tid) * 32 + hv];
    betas[tid] = betabuf[(t0 + tid) * 32 + hv];
  }
  __syncthreads();
  if (tid == 0) {
    float s = 0.f;
    for (int i = 0; i < 64; ++i) { s += gc[i]; gc[i] = s; }
  }
  __syncthreads();
  if (tid < 64) {
    float g = gc[tid];
    gcs[((size_t)hv * 64 + n) * 64 + tid] = g;
    scu[tid] = betas[tid];
    scw[tid] = betas[tid] * expf(g);
  }

  // ---- K K^T via MFMA (global reads; wave owns 16-row m-band) ----
  floatx4 kk[4];
#pragma unroll
  for (int nt = 0; nt < 4; ++nt) kk[nt] = (floatx4){0.f, 0.f, 0.f, 0.f};
#pragma unroll
  for (int ks = 0; ks < 4; ++ks) {
    bf16x8 afr = *(const bf16x8*)&kn[((size_t)(t0 + wv * 16 + l15) * NH_K + hk) * D_K + ks * 32 + quad * 8];
#pragma unroll
    for (int nt = 0; nt < 4; ++nt) {
      bf16x8 bfr = *(const bf16x8*)&kn[((size_t)(t0 + nt * 16 + l15) * NH_K + hk) * D_K + ks * 32 + quad * 8];
      kk[nt] = __builtin_amdgcn_mfma_f32_16x16x32_bf16(afr, bfr, kk[nt], 0, 0, 0);
    }
  }
  // M = strict_tril(beta_i * decay_ij * KKt)
#pragma unroll
  for (int nt = 0; nt < 4; ++nt)
#pragma unroll
    for (int r = 0; r < 4; ++r) {
      int i = wv * 16 + quad * 4 + r;
      int j = nt * 16 + l15;
      float m = 0.f;
      if (j < i) m = kk[nt][r] * betas[i] * expf(fminf(gc[i] - gc[j], 0.f));
      MT[i][j] = m;
    }
  __syncthreads();                    // M + gc/scu/scw visible to all

  // ---- wave 0: barrier-free forward substitution (in-wave LDS order) ----
  if (wv == 0) {
    if (lane == 0) MT[0][0] = 1.f;
    for (int ii = 1; ii < 64; ++ii) {
      float s = 0.f;
      for (int l = 0; l < ii; ++l) s += MT[ii][l] * MT[l][lane];
      MT[ii][lane] = ((lane == ii) ? 1.f : 0.f) - s;
    }
  }
  // ---- attn = tril(decay .* (q @ k^T)), overlapped with subst ----
  {
    int band = (wv == 0) ? 3 : (wv - 1);
    floatx4 at[4];
#pragma unroll
    for (int nt = 0; nt < 4; ++nt) at[nt] = (floatx4){0.f, 0.f, 0.f, 0.f};
#pragma unroll
    for (int ks = 0; ks < 4; ++ks) {
      bf16x8 afr = *(const bf16x8*)&qn[((size_t)(t0 + band * 16 + l15) * NH_K + hk) * D_K + ks * 32 + quad * 8];
#pragma unroll
      for (int nt = 0; nt < 4; ++nt) {
        bf16x8 bfr = *(const bf16x8*)&kn[((size_t)(t0 + nt * 16 + l15) * NH_K + hk) * D_K + ks * 32 + quad * 8];
        at[nt] = __builtin_amdgcn_mfma_f32_16x16x32_bf16(afr, bfr, at[nt], 0, 0, 0);
      }
    }
    size_t abase = ((size_t)hv * 64 + n) * (64 * 64);
#pragma unroll
    for (int nt = 0; nt < 4; ++nt)
#pragma unroll
      for (int r = 0; r < 4; ++r) {
        int i = band * 16 + quad * 4 + r;
        int j = nt * 16 + l15;
        float dec = expf(fminf(gc[i] - gc[j], 0.f));
        float a = (j <= i) ? clampf(at[nt][r] * dec, 1e6f) : 0.f;
        attn[abase + (size_t)i * 64 + j] = (__bf16)a;
      }
  }
  __syncthreads();                    // Tinv complete

  // ---- u = (Tinv diag(scu)) @ v, w = (Tinv diag(scw)) @ k  (hi/lo bf16) ----
  floatx4 ua[8], wa[8];
#pragma unroll
  for (int t = 0; t < 8; ++t) {
    ua[t] = (floatx4){0.f, 0.f, 0.f, 0.f};
    wa[t] = (floatx4){0.f, 0.f, 0.f, 0.f};
  }
#pragma unroll
  for (int ks = 0; ks < 2; ++ks) {
    bf16x8 uh, ul, wh, wl;
#pragma unroll
    for (int j = 0; j < 8; ++j) {
      int c = ks * 32 + quad * 8 + j;
      float raw = MT[wv * 16 + l15][c];
      float tu = raw * scu[c];
      float tw = raw * scw[c];
      __bf16 h1 = (__bf16)tu; uh[j] = h1; ul[j] = (__bf16)(tu - (float)h1);
      __bf16 h2 = (__bf16)tw; wh[j] = h2; wl[j] = (__bf16)(tw - (float)h2);
    }
#pragma unroll
    for (int nt = 0; nt < 8; ++nt) {
      bf16x8 vb = *(const bf16x8*)&vT[nt * 16 + l15][ks * 32 + quad * 8];
      ua[nt] = __builtin_amdgcn_mfma_f32_16x16x32_bf16(uh, vb, ua[nt], 0, 0, 0);
      ua[nt] = __builtin_amdgcn_mfma_f32_16x16x32_bf16(ul, vb, ua[nt], 0, 0, 0);
      bf16x8 kb = *(const bf16x8*)&kT[nt * 16 + l15][ks * 32 + quad * 8];
      wa[nt] = __builtin_amdgcn_mfma_f32_16x16x32_bf16(wh, kb, wa[nt], 0, 0, 0);
      wa[nt] = __builtin_amdgcn_mfma_f32_16x16x32_bf16(wl, kb, wa[nt], 0, 0, 0);
    }
  }
  size_t base = ((size_t)hv * 64 + n) * (64 * 128);
#pragma unroll
  for (int nt = 0; nt < 8; ++nt)
#pragma unroll
    for (int r = 0; r < 4; ++r) {
      int row = wv * 16 + quad * 4 + r;
      int dv  = nt * 16 + l15;
      u[base + (size_t)row * 128 + dv] = (__bf16)clampf(ua[nt][r], 1e6f);
      w[base + (size_t)row * 128 + dv] = (__bf16)clampf(wa[nt][r], 1e6f);
    }
}

// ---------------------------------------------------------------------------
// Sequential inter-chunk scan — MFMA, single-wave-per-block version.
// Grid = 8 dv-bands x 32 heads (blockIdx = band*32 + hv so all 8 bands of a
// head land on the SAME XCD). One wave per block: no __syncthreads anywhere.
// S (fp32) in MFMA accumulators; round-tripped via LDS as bf16 hi/lo.
// ---------------------------------------------------------------------------
__global__ __launch_bounds__(64, 1) void scan_kernel(
    const __bf16* __restrict__ u, const __bf16* __restrict__ w, const __bf16* __restrict__ attn,
    const __bf16* __restrict__ qn, const __bf16* __restrict__ kn, const float* __restrict__ gcs,
    __bf16* __restrict__ obuf)
{
  __shared__ __bf16 sb_hi[16][136];   // S^T hi: [dv][dk] (272B rows: 2-way banks, free)
  __shared__ __bf16 sb_lo[16][136];   // S^T lo
  __shared__ __bf16 vt[16][72];       // v_new^T: [dv][t]
  __shared__ __bf16 kt[128][72];      // k^T: [dk][t] (no decay — folded into vfd)

  const int hv   = blockIdx.x & 31;   // XCD = blockIdx%8 = hv%8 -> bands colocate
  const int band = blockIdx.x >> 5;
  const int dv0  = band * 16;
  const int hk   = hv >> 1;
  const int lane = threadIdx.x;
  const int l15  = lane & 15;
  const int quad = lane >> 4;

  floatx4 S[8];                       // S[dk = m*16+quad*4+r][dv = l15]
#pragma unroll
  for (int m = 0; m < 8; ++m) S[m] = (floatx4){0.f, 0.f, 0.f, 0.f};
  for (int i = lane; i < 16 * 136 / 2; i += 64) {
    ((unsigned int*)sb_hi)[i] = 0u;
    ((unsigned int*)sb_lo)[i] = 0u;
  }

  for (int n = 0; n < 64; ++n) {
    const int t0 = n * 64;
    const size_t cb = (size_t)hv * 64 + n;
    const float* gr = gcs + cb * 64;
    const size_t ub = cb * 8192;

    // ---- issue k row load early (lane owns t = lane); staged to kt later ----
    const __bf16* krow = &kn[((size_t)(t0 + lane) * NH_K + hk) * D_K];
    bf16x8 kr[16];
#pragma unroll
    for (int c2 = 0; c2 < 16; ++c2) kr[c2] = *(const bf16x8*)&krow[c2 * 8];

    // ---- u init (C-layout: row=quad*4+r, col=l15) ----
    floatx4 av[4];
#pragma unroll
    for (int mt = 0; mt < 4; ++mt)
#pragma unroll
      for (int r = 0; r < 4; ++r)
        av[mt][r] = (float)u[ub + (size_t)(mt * 16 + quad * 4 + r) * 128 + dv0 + l15];

    // ---- prev-chunk S fragments (B: n=l15, k=quad*8+j) ----
    bf16x8 sh[4], sl[4];
#pragma unroll
    for (int ks = 0; ks < 4; ++ks) {
      sh[ks] = *(const bf16x8*)&sb_hi[l15][ks * 32 + quad * 8];
      sl[ks] = *(const bf16x8*)&sb_lo[l15][ks * 32 + quad * 8];
    }

    // ---- m1: v_new = u + (-w)@(S_hi + S_lo) ----
#pragma unroll
    for (int ks = 0; ks < 4; ++ks)
#pragma unroll
      for (int mt = 0; mt < 4; ++mt) {
        uint32x4 wu = *(const uint32x4*)&w[ub + (size_t)(mt * 16 + l15) * 128 + ks * 32 + quad * 8];
        wu[0] ^= 0x80008000u; wu[1] ^= 0x80008000u;
        wu[2] ^= 0x80008000u; wu[3] ^= 0x80008000u;
        bf16x8 wf = __builtin_bit_cast(bf16x8, wu);
        av[mt] = __builtin_amdgcn_mfma_f32_16x16x32_bf16(wf, sh[ks], av[mt], 0, 0, 0);
        av[mt] = __builtin_amdgcn_mfma_f32_16x16x32_bf16(wf, sl[ks], av[mt], 0, 0, 0);
      }
    // write v_new^T
#pragma unroll
    for (int mt = 0; mt < 4; ++mt) {
      bf16x4 h4;
#pragma unroll
      for (int r = 0; r < 4; ++r) h4[r] = (__bf16)clampf(av[mt][r], 1e8f);
      *(bf16x4*)&vt[l15][mt * 16 + quad * 4] = h4;
    }

    // ---- gates ----
    const float gl  = gr[63];
    const float egl = expf(gl);
    float egr[16];
#pragma unroll
    for (int mt = 0; mt < 4; ++mt)
#pragma unroll
      for (int r = 0; r < 4; ++r)
        egr[mt * 4 + r] = expf(gr[mt * 16 + quad * 4 + r]);
    float ek0[8], ek1[8];
#pragma unroll
    for (int j = 0; j < 8; ++j) {
      ek0[j] = expf(fminf(gl - gr[quad * 8 + j], 0.f));
      ek1[j] = expf(fminf(gl - gr[32 + quad * 8 + j], 0.f));
    }

    // ---- m3: o = diag(exp(g)) * (q @ S) ----
    floatx4 ao[4];
#pragma unroll
    for (int mt = 0; mt < 4; ++mt) ao[mt] = (floatx4){0.f, 0.f, 0.f, 0.f};
#pragma unroll
    for (int ks = 0; ks < 4; ++ks)
#pragma unroll
      for (int mt = 0; mt < 4; ++mt) {
        bf16x8 qf = *(const bf16x8*)&qn[((size_t)(t0 + mt * 16 + l15) * NH_K + hk) * D_K + ks * 32 + quad * 8];
        ao[mt] = __builtin_amdgcn_mfma_f32_16x16x32_bf16(qf, sh[ks], ao[mt], 0, 0, 0);
        ao[mt] = __builtin_amdgcn_mfma_f32_16x16x32_bf16(qf, sl[ks], ao[mt], 0, 0, 0);
      }
#pragma unroll
    for (int mt = 0; mt < 4; ++mt)
#pragma unroll
      for (int r = 0; r < 4; ++r) ao[mt][r] *= egr[mt * 4 + r];

    // ---- stage kt (kn loads have had m1+m3 to arrive). Lane writes column
    //      t=lane: per dk step all 64 lanes span 128B -> conflict-free. ----
#pragma unroll
    for (int c2 = 0; c2 < 16; ++c2)
#pragma unroll
      for (int j = 0; j < 8; ++j)
        kt[c2 * 8 + j][lane] = kr[c2][j];

    // ---- m3b: o += attn @ v_new ----
    bf16x8 vf0 = *(const bf16x8*)&vt[l15][quad * 8];
    bf16x8 vf1 = *(const bf16x8*)&vt[l15][32 + quad * 8];
#pragma unroll
    for (int mt = 0; mt < 4; ++mt) {
      bf16x8 a0 = *(const bf16x8*)&attn[cb * 4096 + (size_t)(mt * 16 + l15) * 64 + quad * 8];
      bf16x8 a1 = *(const bf16x8*)&attn[cb * 4096 + (size_t)(mt * 16 + l15) * 64 + 32 + quad * 8];
      ao[mt] = __builtin_amdgcn_mfma_f32_16x16x32_bf16(a0, vf0, ao[mt], 0, 0, 0);
      ao[mt] = __builtin_amdgcn_mfma_f32_16x16x32_bf16(a1, vf1, ao[mt], 0, 0, 0);
    }
#pragma unroll
    for (int mt = 0; mt < 4; ++mt)
#pragma unroll
      for (int r = 0; r < 4; ++r)
        obuf[((size_t)(t0 + mt * 16 + quad * 4 + r) * NH_V + hv) * D_V + dv0 + l15]
            = (__bf16)clampf(ao[mt][r], 1e8f);

    // ---- m4: S = exp(gl)*S + k^T @ (v_new * exp(gl-g)) ----
#pragma unroll
    for (int m = 0; m < 8; ++m)
#pragma unroll
      for (int r = 0; r < 4; ++r) S[m][r] *= egl;
    bf16x8 vfd0, vfd1;
#pragma unroll
    for (int j = 0; j < 8; ++j) {
      vfd0[j] = (__bf16)((float)vf0[j] * ek0[j]);
      vfd1[j] = (__bf16)((float)vf1[j] * ek1[j]);
    }
#pragma unroll
    for (int ks = 0; ks < 2; ++ks) {
      bf16x8 vf = ks ? vfd1 : vfd0;
#pragma unroll
      for (int m = 0; m < 8; ++m) {
        bf16x8 kf = *(const bf16x8*)&kt[m * 16 + l15][ks * 32 + quad * 8];
        S[m] = __builtin_amdgcn_mfma_f32_16x16x32_bf16(kf, vf, S[m], 0, 0, 0);
      }
    }
    // clamp + dump S^T hi/lo
#pragma unroll
    for (int m = 0; m < 8; ++m) {
      bf16x4 h4, l4;
#pragma unroll
      for (int r = 0; r < 4; ++r) {
        float v = clampf(S[m][r], 1e8f);
        S[m][r] = v;
        __bf16 h = (__bf16)v;
        h4[r] = h;
        l4[r] = (__bf16)(v - (float)h);
      }
      *(bf16x4*)&sb_hi[l15][m * 16 + quad * 4] = h4;
      *(bf16x4*)&sb_lo[l15][m * 16 + quad * 4] = l4;
    }
  }
}

// ---------------------------------------------------------------------------
// Gated RMS norm: wave per (t,hv) row, bf16x2 loads, shfl reduce, 0 barriers.
// ---------------------------------------------------------------------------
__global__ __launch_bounds__(256) void gate_kernel(
    const __bf16* __restrict__ obuf, const __bf16* __restrict__ qkvz,
    const void* __restrict__ norm_w, __bf16* __restrict__ og,
    const int* __restrict__ flagp)
{
  const bool f32 = (*flagp != 0);
  const int t = blockIdx.x;
  const int wv = threadIdx.x >> 6, lane = threadIdx.x & 63;
  const int hv = blockIdx.y * 4 + wv;
  const int d = lane * 2;
  bf16x2 ov = *(const bf16x2*)&obuf[((size_t)t * NH_V + hv) * D_V + d];
  bf16x2 zv = *(const bf16x2*)&qkvz[(size_t)t * QKVZ_COLS + (hv >> 1) * 768 + 512 + (hv & 1) * 128 + d];
  float z0 = (float)zv[0], z1 = (float)zv[1];
  float v0 = (float)ov[0] * (z0 * sigm(z0));
  float v1 = (float)ov[1] * (z1 * sigm(z1));
  float ss = v0 * v0 + v1 * v1;
#pragma unroll
  for (int off = 32; off; off >>= 1) ss += __shfl_xor(ss, off, 64);
  float scl = rsqrtf(ss * (1.f / 128.f) + 1e-6f);
  bf16x2 o;
  o[0] = (__bf16)(v0 * scl * loadF(norm_w, d, f32));
  o[1] = (__bf16)(v1 * scl * loadF(norm_w, d + 1, f32));
  *(bf16x2*)&og[(size_t)t * 4096 + hv * 128 + d] = o;
}

// ---------------------------------------------------------------------------
extern "C" void kernel_launch(void* const* d_in, const int* in_sizes, int n_in,
                              void* d_out, int out_size, void* d_ws, size_t ws_size,
                              hipStream_t stream) {
  (void)in_sizes; (void)n_in; (void)out_size;
  const void* x     = d_in[0];
  const void* Wqkvz = d_in[3];
  const void* Wba   = d_in[4];
  const void* convw = d_in[5];
  const void* dtb   = d_in[6];
  const void* Alog  = d_in[7];
  const void* normw = d_in[8];
  const void* Wout  = d_in[9];

  char* ws = (char*)d_ws;
  size_t off = 0;
  int*    flag = (int*)(ws + off);    off += 256;
  __bf16* qkvz = (__bf16*)(ws + off); off += (size_t)4096 * 12288 * 2;
  float* ba    = (float*)(ws + off);  off += (size_t)4096 * 64 * 4;
  float* gbuf  = (float*)(ws + off);  off += (size_t)4096 * 32 * 4;
  float* betab = (float*)(ws + off);  off += (size_t)4096 * 32 * 4;
  float* gcs   = (float*)(ws + off);  off += (size_t)32 * 64 * 64 * 4;
  __bf16* qn   = (__bf16*)(ws + off); off += (size_t)4096 * 2048 * 2;
  __bf16* kn   = (__bf16*)(ws + off); off += (size_t)4096 * 2048 * 2;
  __bf16* vv   = (__bf16*)(ws + off); off += (size_t)4096 * 4096 * 2;
  __bf16* ubuf = (__bf16*)(ws + off); off += (size_t)32 * 64 * 8192 * 2;
  __bf16* wbuf = (__bf16*)(ws + off); off += (size_t)32 * 64 * 8192 * 2;
  __bf16* attn = (__bf16*)(ws + off); off += (size_t)32 * 64 * 4096 * 2;
  __bf16* obuf = vv;      // overlay: vv dead after prep
  __bf16* og   = ubuf;    // overlay: ubuf dead after scan (og = 4096x4096 bf16 = 33.5MB)
  // pre-GEMM bf16 operand overlays (all dead before their regions' writers run):
  __bf16* WqkvzT = ubuf;  // 12288x2048 bf16 = 50.3MB <= ubuf+wbuf (67.1MB); dead before prep
  __bf16* xb     = attn;  // 4096x2048 bf16 = 16.8MB = attn size; dead before prep
  __bf16* WoutT  = wbuf;  // 2048x4096 bf16 = 16.8MB <= wbuf; written after scan
  if (ws_size < off) return;

  detect_kernel<<<1, 256, 0, stream>>>((const unsigned int*)x, flag);
  convx_kernel<<<4096, 256, 0, stream>>>(x, xb, flag);
  trans_kernel<<<dim3(64, 384), 256, 0, stream>>>(Wqkvz, WqkvzT, 2048, 12288, flag);
  gemm_bt2<false><<<dim3(48, 16), 512, 0, stream>>>(xb, WqkvzT, qkvz, 4096, 12288, 2048);
  ba_kernel<<<4096, 64, 0, stream>>>(x, Wba, ba, flag);
  conv_kernel<<<dim3(64, 16), 256, 0, stream>>>(qkvz, convw, qn, kn, vv, flag);
  gb_kernel<<<4096, 64, 0, stream>>>(ba, dtb, Alog, gbuf, betab, flag);
  prep_kernel<<<2048, 256, 0, stream>>>(qn, kn, vv, gbuf, betab, gcs, ubuf, wbuf, attn);
  scan_kernel<<<256, 64, 0, stream>>>(ubuf, wbuf, attn, qn, kn, gcs, obuf);
  gate_kernel<<<dim3(4096, 8), 256, 0, stream>>>(obuf, qkvz, normw, og, flag);
  trans_kernel<<<dim3(128, 64), 256, 0, stream>>>(Wout, WoutT, 4096, 2048, flag);
  gemm_bt2<true><<<dim3(8, 16), 512, 0, stream>>>(og, WoutT, d_out, 4096, 2048, 4096);
}

// Round 8
// 1389.712 us; speedup vs baseline: 1.0694x; 1.0694x over previous
//
#include <hip/hip_runtime.h>
#include <hip/hip_bf16.h>

#define NH_K 16
#define NH_V 32
#define D_K 128
#define D_V 128
#define QKVZ_COLS 12288

typedef __attribute__((ext_vector_type(8))) __bf16 bf16x8;
typedef __attribute__((ext_vector_type(4))) __bf16 bf16x4;
typedef __attribute__((ext_vector_type(2))) __bf16 bf16x2;
typedef __attribute__((ext_vector_type(4))) float floatx4;
typedef __attribute__((ext_vector_type(4))) unsigned int uint32x4;

// global_load_lds: LDS dest = wave-uniform base + lane*16; global src per-lane.
#define GLDS16(gp, lp) __builtin_amdgcn_global_load_lds( \
    (const __attribute__((address_space(1))) unsigned int*)(gp), \
    (__attribute__((address_space(3))) unsigned int*)(lp), 16, 0, 0)

__device__ __forceinline__ float sigm(float x) {
  float e = expf(-fabsf(x));
  return (x >= 0.f) ? 1.f / (1.f + e) : e / (1.f + e);
}
__device__ __forceinline__ float clampf(float v, float m) {
  return fminf(fmaxf(v, -m), m);      // scrubs NaN too
}
// dtype-flexible scalar load: flag chooses fp32 vs bf16 interpretation
__device__ __forceinline__ float loadF(const void* p, size_t i, bool f32) {
  return f32 ? ((const float*)p)[i] : (float)((const __bf16*)p)[i];
}

// ---------------------------------------------------------------------------
// Input dtype sniffer (validated: flags fp32 correctly).
// ---------------------------------------------------------------------------
__global__ __launch_bounds__(256) void detect_kernel(
    const unsigned int* __restrict__ x, int* __restrict__ flag)
{
  __shared__ int cnt;
  if (threadIdx.x == 0) cnt = 0;
  __syncthreads();
  unsigned int w = x[threadIdx.x];
  int e = (w >> 7) & 0xFF;
  if (e >= 100 && e <= 135) atomicAdd(&cnt, 1);
  __syncthreads();
  if (threadIdx.x == 0) *flag = (cnt < 128) ? 1 : 0;   // 1 = fp32 inputs
}

// ---------------------------------------------------------------------------
// x (fp32 or bf16) -> xb (bf16), 8 elems/thread, fully coalesced.
// ---------------------------------------------------------------------------
__global__ __launch_bounds__(256) void convx_kernel(
    const void* __restrict__ x, __bf16* __restrict__ xb,
    const int* __restrict__ flagp)
{
  const bool f32 = (*flagp != 0);
  size_t i = ((size_t)blockIdx.x * 256 + threadIdx.x) * 8;
  if (f32) {
    float4 a = *(const float4*)&((const float*)x)[i];
    float4 b = *(const float4*)&((const float*)x)[i + 4];
    bf16x8 v;
    v[0]=(__bf16)a.x; v[1]=(__bf16)a.y; v[2]=(__bf16)a.z; v[3]=(__bf16)a.w;
    v[4]=(__bf16)b.x; v[5]=(__bf16)b.y; v[6]=(__bf16)b.z; v[7]=(__bf16)b.w;
    *(bf16x8*)&xb[i] = v;
  } else {
    *(uint32x4*)&xb[i] = *(const uint32x4*)&((const __bf16*)x)[i];
  }
}

// ---------------------------------------------------------------------------
// Transpose+convert: W[K][N] (fp32 or bf16) -> WT[N][K] bf16. 32x32 LDS tile.
// ---------------------------------------------------------------------------
__global__ __launch_bounds__(256) void trans_kernel(
    const void* __restrict__ W, __bf16* __restrict__ WT,
    int K, int N, const int* __restrict__ flagp)
{
  const bool f32 = (*flagp != 0);
  __shared__ float t[32][33];
  const int k0 = blockIdx.x * 32, n0 = blockIdx.y * 32;
  const int tid = threadIdx.x;
  {
    int r = tid >> 3, c4 = (tid & 7) * 4;
    if (f32) {
      float4 v = *(const float4*)&((const float*)W)[(size_t)(k0 + r) * N + n0 + c4];
      t[r][c4] = v.x; t[r][c4 + 1] = v.y; t[r][c4 + 2] = v.z; t[r][c4 + 3] = v.w;
    } else {
      bf16x4 v = *(const bf16x4*)&((const __bf16*)W)[(size_t)(k0 + r) * N + n0 + c4];
      t[r][c4] = (float)v[0]; t[r][c4 + 1] = (float)v[1];
      t[r][c4 + 2] = (float)v[2]; t[r][c4 + 3] = (float)v[3];
    }
  }
  __syncthreads();
  {
    int n = tid >> 3, k4 = (tid & 7) * 4;
    bf16x4 o;
#pragma unroll
    for (int j = 0; j < 4; ++j) o[j] = (__bf16)t[k4 + j][n];
    *(bf16x4*)&WT[(size_t)(n0 + n) * K + k0 + k4] = o;
  }
}

// ---------------------------------------------------------------------------
// 128x128 m97-structure MFMA GEMM (for N=2048 Wout GEMM: 512 blocks).
// ---------------------------------------------------------------------------
template<bool OUT_F32>
__global__ __launch_bounds__(256) void gemm_bt(
    const __bf16* __restrict__ A, const __bf16* __restrict__ BT,
    void* __restrict__ C, int M, int N, int K)
{
  __shared__ __align__(16) __bf16 As[128 * 32];
  __shared__ __align__(16) __bf16 Bs[128 * 32];
  const int tid = threadIdx.x;
  const int nx  = gridDim.x;
  const int nwg = nx * gridDim.y;
  int lid = blockIdx.y * nx + blockIdx.x;
  int swz = (lid & 7) * (nwg >> 3) + (lid >> 3);   // nwg % 8 == 0 (bijective)
  const int bn = (swz % nx) * 128;
  const int bm = (swz / nx) * 128;
  const int lane = tid & 63;
  const int wv   = tid >> 6;
  const int wm   = (wv >> 1) * 64;
  const int wn   = (wv & 1) * 64;
  const int l15  = lane & 15;
  const int quad = lane >> 4;

  const int o0 = wv * 2048 + lane * 16;
  const int o1 = o0 + 1024;
  const __bf16* Ag0 = &A[(size_t)(bm + (o0 >> 6)) * K + ((o0 & 63) >> 1)];
  const __bf16* Ag1 = &A[(size_t)(bm + (o1 >> 6)) * K + ((o1 & 63) >> 1)];
  const __bf16* Bg0 = &BT[(size_t)(bn + (o0 >> 6)) * K + ((o0 & 63) >> 1)];
  const __bf16* Bg1 = &BT[(size_t)(bn + (o1 >> 6)) * K + ((o1 & 63) >> 1)];
  __bf16* Ad0 = &As[wv * 1024];
  __bf16* Ad1 = &As[wv * 1024 + 512];
  __bf16* Bd0 = &Bs[wv * 1024];
  __bf16* Bd1 = &Bs[wv * 1024 + 512];

  floatx4 acc[4][4];
#pragma unroll
  for (int a = 0; a < 4; ++a)
#pragma unroll
    for (int b = 0; b < 4; ++b)
      acc[a][b] = (floatx4){0.f, 0.f, 0.f, 0.f};

  for (int k0 = 0; k0 < K; k0 += 32) {
    GLDS16(Ag0 + k0, Ad0);
    GLDS16(Ag1 + k0, Ad1);
    GLDS16(Bg0 + k0, Bd0);
    GLDS16(Bg1 + k0, Bd1);
    __syncthreads();
    bf16x8 af[4], bfr[4];
#pragma unroll
    for (int mt = 0; mt < 4; ++mt)
      af[mt] = *(const bf16x8*)&As[(wm + mt * 16 + l15) * 32 + quad * 8];
#pragma unroll
    for (int nt = 0; nt < 4; ++nt)
      bfr[nt] = *(const bf16x8*)&Bs[(wn + nt * 16 + l15) * 32 + quad * 8];
#pragma unroll
    for (int mt = 0; mt < 4; ++mt)
#pragma unroll
      for (int nt = 0; nt < 4; ++nt)
        acc[mt][nt] = __builtin_amdgcn_mfma_f32_16x16x32_bf16(af[mt], bfr[nt], acc[mt][nt], 0, 0, 0);
    __syncthreads();
  }
#pragma unroll
  for (int mt = 0; mt < 4; ++mt)
#pragma unroll
    for (int nt = 0; nt < 4; ++nt)
#pragma unroll
      for (int r = 0; r < 4; ++r) {
        int row = bm + wm + mt * 16 + quad * 4 + r;
        int col = bn + wn + nt * 16 + l15;
        if (OUT_F32) ((float*)C)[(size_t)row * N + col] = acc[mt][nt][r];
        else         ((__bf16*)C)[(size_t)row * N + col] = (__bf16)acc[mt][nt][r];
      }
}

// ---------------------------------------------------------------------------
// 256x256 MFMA GEMM with counted-vmcnt double-buffer (T4) + st_16x32 LDS
// swizzle (T2). For the big qkvz GEMM (grid 48x16 = 768 blocks).
// ---------------------------------------------------------------------------
template<bool OUT_F32>
__global__ __launch_bounds__(512, 1) void gemm_bt2(
    const __bf16* __restrict__ A, const __bf16* __restrict__ BT,
    void* __restrict__ C, int M, int N, int K)
{
  __shared__ __align__(16) __bf16 As[2][8192];   // [slot][256 rows x 32 cols]
  __shared__ __align__(16) __bf16 Bs[2][8192];
  const int tid = threadIdx.x;
  const int nx  = gridDim.x;
  const int nwg = nx * gridDim.y;
  int lid = blockIdx.y * nx + blockIdx.x;
  int swz = (lid & 7) * (nwg >> 3) + (lid >> 3);   // nwg % 8 == 0 (bijective)
  const int bn = (swz % nx) * 256;
  const int bm = (swz / nx) * 256;
  const int lane = tid & 63;
  const int wv   = tid >> 6;          // 0..7
  const int wm2  = wv >> 2;           // M-half (0..1)
  const int wn2  = wv & 3;            // N-quarter (0..3)
  const int l15  = lane & 15;
  const int quad = lane >> 4;
  const int NT   = K >> 5;

  auto stage = [&](int kt, int slot) {
    const int k0 = kt * 32;
#pragma unroll
    for (int L = 0; L < 2; ++L) {
      const int boff = L * 8192 + wv * 1024 + lane * 16;
      const int swb  = boff ^ (((boff >> 9) & 1) << 5);
      const int row  = swb >> 6;           // 64B per row
      const int ce   = (swb & 63) >> 1;    // col element
      GLDS16(&A[(size_t)(bm + row) * K + k0 + ce], &As[slot][L * 4096 + wv * 512]);
      GLDS16(&BT[(size_t)(bn + row) * K + k0 + ce], &Bs[slot][L * 4096 + wv * 512]);
    }
  };

  floatx4 acc[8][4];
#pragma unroll
  for (int a = 0; a < 8; ++a)
#pragma unroll
    for (int b = 0; b < 4; ++b)
      acc[a][b] = (floatx4){0.f, 0.f, 0.f, 0.f};

  const int flip  = (l15 & 8) ? 32 : 0;
  const int baseA = (((wm2 * 128 + l15) * 64 + quad * 16) ^ flip);
  const int baseB = (((wn2 * 64 + l15) * 64 + quad * 16) ^ flip);

  stage(0, 0);
  stage(1, 1);
  asm volatile("s_waitcnt vmcnt(4)" ::: "memory");
  __builtin_amdgcn_s_barrier();
  __builtin_amdgcn_sched_barrier(0);

  for (int kt = 0; kt < NT; ++kt) {
    const int cur = kt & 1;
    const char* Ab = (const char*)&As[cur][0];
    const char* Bb = (const char*)&Bs[cur][0];
    bf16x8 af[8], bfr[4];
#pragma unroll
    for (int mt = 0; mt < 8; ++mt)
      af[mt] = *(const bf16x8*)(Ab + baseA + mt * 1024);
#pragma unroll
    for (int nt = 0; nt < 4; ++nt)
      bfr[nt] = *(const bf16x8*)(Bb + baseB + nt * 1024);
#pragma unroll
    for (int mt = 0; mt < 8; ++mt)
#pragma unroll
      for (int nt = 0; nt < 4; ++nt)
        acc[mt][nt] = __builtin_amdgcn_mfma_f32_16x16x32_bf16(af[mt], bfr[nt], acc[mt][nt], 0, 0, 0);
    if (kt + 1 < NT) {
      __builtin_amdgcn_s_barrier();               // all waves done reading cur
      if (kt + 2 < NT) {
        stage(kt + 2, cur);                       // refill freed slot
        asm volatile("s_waitcnt vmcnt(4)" ::: "memory");   // kt+1 landed
      } else {
        asm volatile("s_waitcnt vmcnt(0)" ::: "memory");
      }
      __builtin_amdgcn_s_barrier();               // kt+1 visible to all waves
      __builtin_amdgcn_sched_barrier(0);
    }
  }

#pragma unroll
  for (int mt = 0; mt < 8; ++mt)
#pragma unroll
    for (int nt = 0; nt < 4; ++nt)
#pragma unroll
      for (int r = 0; r < 4; ++r) {
        int row = bm + wm2 * 128 + mt * 16 + quad * 4 + r;
        int col = bn + wn2 * 64 + nt * 16 + l15;
        if (OUT_F32) ((float*)C)[(size_t)row * N + col] = acc[mt][nt][r];
        else         ((__bf16*)C)[(size_t)row * N + col] = (__bf16)acc[mt][nt][r];
      }
}

// ---------------------------------------------------------------------------
__global__ __launch_bounds__(64) void ba_kernel(
    const void* __restrict__ x, const void* __restrict__ Wba,
    float* __restrict__ ba, const int* __restrict__ flagp)
{
  __shared__ float xr[2048];
  const bool f32 = (*flagp != 0);
  int t = blockIdx.x, tid = threadIdx.x;
  for (int i = tid; i < 2048; i += 64) xr[i] = loadF(x, (size_t)t * 2048 + i, f32);
  __syncthreads();
  float acc = 0.f;
  for (int k = 0; k < 2048; ++k) acc += xr[k] * loadF(Wba, (size_t)k * 64 + tid, f32);
  ba[(size_t)t * 64 + tid] = acc;
}

// ---------------------------------------------------------------------------
// Scrambled depthwise conv (torch cat->transpose->reshape), silu, l2norm q/k.
// ---------------------------------------------------------------------------
__global__ __launch_bounds__(256) void conv_kernel(
    const __bf16* __restrict__ qkvz, const void* __restrict__ conv_w,
    __bf16* __restrict__ qn, __bf16* __restrict__ kn, __bf16* __restrict__ vv,
    const int* __restrict__ flagp)
{
  __shared__ __bf16 yin[128][266];    // window: i in [0,264) <-> s2 = t0-8+i
  const bool f32 = (*flagp != 0);
  const int slot = blockIdx.x;        // 0..63
  const int tb   = blockIdx.y;        // 0..15
  const int tid  = threadIdx.x;
  int kind, h_out, cbase;
  if (slot < 16)      { kind = 0; h_out = slot;      cbase = slot * 128; }
  else if (slot < 32) { kind = 1; h_out = slot - 16; cbase = 2048 + h_out * 128; }
  else                { kind = 2; h_out = slot - 32; cbase = 4096 + h_out * 128; }
  const int hc  = cbase >> 9;
  const int cl0 = cbase & 511;
  const int t0  = tb * 256;

  for (int ch = tid; ch < 128 * 33; ch += 256) {
    int d = ch / 33, k = ch - d * 33;
    int s2 = t0 - 8 + k * 8;
    uint32x4 val;
    if (s2 < 0) {
      val = (uint32x4){0u, 0u, 0u, 0u};
    } else {
      int p  = (cl0 + d) * 4096 + s2;
      int tp = p >> 9, ep = p & 511;
      val = *(const uint32x4*)&qkvz[(size_t)tp * QKVZ_COLS + hc * 768 + ep];
    }
    unsigned int* dst = (unsigned int*)&yin[d][k * 8];
    dst[0] = val[0]; dst[1] = val[1]; dst[2] = val[2]; dst[3] = val[3];
  }
  __syncthreads();

  const int wv   = tid >> 6;
  const int lane = tid & 63;
  float w0[4], w1[4];
#pragma unroll
  for (int j = 0; j < 4; ++j) {
    w0[j] = loadF(conv_w, (size_t)(cbase + lane) * 4 + j, f32);
    w1[j] = loadF(conv_w, (size_t)(cbase + lane + 64) * 4 + j, f32);
  }
  const int ltend = wv * 64 + 64;
  for (int lt = wv * 64; lt < ltend; ++lt) {
    int t = t0 + lt;
    float a0 = 0.f, a1 = 0.f;
#pragma unroll
    for (int j = 0; j < 4; ++j) {
      a0 += w0[j] * (float)yin[lane][lt + 5 + j];
      a1 += w1[j] * (float)yin[lane + 64][lt + 5 + j];
    }
    float v0 = a0 * sigm(a0), v1 = a1 * sigm(a1);
    if (kind == 2) {
      vv[((size_t)t * NH_V + h_out) * D_V + lane]      = (__bf16)v0;
      vv[((size_t)t * NH_V + h_out) * D_V + lane + 64] = (__bf16)v1;
    } else {
      float ss = v0 * v0 + v1 * v1;
#pragma unroll
      for (int off = 32; off; off >>= 1) ss += __shfl_xor(ss, off, 64);
      float scl = rsqrtf(ss + 1e-6f);
      if (kind == 0) scl *= 0.08838834764831845f;   // DK^-0.5
      __bf16* dst = (kind == 0) ? qn : kn;
      dst[((size_t)t * NH_K + h_out) * D_K + lane]      = (__bf16)(v0 * scl);
      dst[((size_t)t * NH_K + h_out) * D_K + lane + 64] = (__bf16)(v1 * scl);
    }
  }
}

// ---------------------------------------------------------------------------
__global__ __launch_bounds__(64) void gb_kernel(
    const float* __restrict__ ba, const void* __restrict__ dt_bias,
    const void* __restrict__ A_log, float* __restrict__ gbuf,
    float* __restrict__ betabuf, const int* __restrict__ flagp)
{
  const bool f32 = (*flagp != 0);
  int t = blockIdx.x;
  int hv = threadIdx.x;
  if (hv >= 32) return;
  float bv = ba[t * 64 + (hv >> 1) * 4 + (hv & 1)];
  float av = ba[t * 64 + (hv >> 1) * 4 + 2 + (hv & 1)];
  float beta = sigm(bv);
  float xx = av + loadF(dt_bias, hv, f32);
  float sp = (xx > 15.f) ? xx : log1pf(expf(fminf(xx, 15.f)));
  float g = -expf(loadF(A_log, hv, f32)) * sp;
  gbuf[t * 32 + hv] = g;
  betabuf[t * 32 + hv] = beta;
}

// ---------------------------------------------------------------------------
// Per-(head,chunk): g cumsum, M (MFMA), Tinv (1-wave barrier-free subst,
// overlapped with attn MFMA on waves 1-3), u/w (MFMA, Tinv hi/lo).
// ---------------------------------------------------------------------------
__global__ __launch_bounds__(256) void prep_kernel(
    const __bf16* __restrict__ qn, const __bf16* __restrict__ kn, const __bf16* __restrict__ vv,
    const float* __restrict__ gbuf, const float* __restrict__ betabuf,
    float* __restrict__ gcs, __bf16* __restrict__ u, __bf16* __restrict__ w,
    __bf16* __restrict__ attn)
{
  __shared__ float MT[64][67];
  __shared__ __bf16 vT[128][72];
  __shared__ __bf16 kT[128][72];
  __shared__ float gc[64], betas[64], scu[64], scw[64];
  const int bid = blockIdx.x;
  const int hv = bid >> 6, n = bid & 63;
  const int hk = hv >> 1;
  const int t0 = n * 64;
  const int tid = threadIdx.x;
  const int wv = tid >> 6, lane = tid & 63;
  const int l15 = lane & 15, quad = lane >> 4;

  {
    const __bf16* vrow = &vv[((size_t)(t0 + lane) * NH_V + hv) * D_V + wv * 32];
    const __bf16* krow = &kn[((size_t)(t0 + lane) * NH_K + hk) * D_K + wv * 32];
#pragma unroll
    for (int c2 = 0; c2 < 4; ++c2) {
      bf16x8 v8 = *(const bf16x8*)&vrow[c2 * 8];
      bf16x8 k8 = *(const bf16x8*)&krow[c2 * 8];
#pragma unroll
      for (int j = 0; j < 8; ++j) {
        vT[wv * 32 + c2 * 8 + j][lane] = v8[j];
        kT[wv * 32 + c2 * 8 + j][lane] = k8[j];
      }
    }
  }
  if (tid < 64) {
    gc[tid]    = gbuf[(t0 + tid) * 32 + hv];
    betas[tid] = betabuf[(t0 + tid) * 32 + hv];
  }
  __syncthreads();
  if (tid == 0) {
    float s = 0.f;
    for (int i = 0; i < 64; ++i) { s += gc[i]; gc[i] = s; }
  }
  __syncthreads();
  if (tid < 64) {
    float g = gc[tid];
    gcs[((size_t)hv * 64 + n) * 64 + tid] = g;
    scu[tid] = betas[tid];
    scw[tid] = betas[tid] * expf(g);
  }

  floatx4 kk[4];
#pragma unroll
  for (int nt = 0; nt < 4; ++nt) kk[nt] = (floatx4){0.f, 0.f, 0.f, 0.f};
#pragma unroll
  for (int ks = 0; ks < 4; ++ks) {
    bf16x8 afr = *(const bf16x8*)&kn[((size_t)(t0 + wv * 16 + l15) * NH_K + hk) * D_K + ks * 32 + quad * 8];
#pragma unroll
    for (int nt = 0; nt < 4; ++nt) {
      bf16x8 bfr = *(const bf16x8*)&kn[((size_t)(t0 + nt * 16 + l15) * NH_K + hk) * D_K + ks * 32 + quad * 8];
      kk[nt] = __builtin_amdgcn_mfma_f32_16x16x32_bf16(afr, bfr, kk[nt], 0, 0, 0);
    }
  }
#pragma unroll
  for (int nt = 0; nt < 4; ++nt)
#pragma unroll
    for (int r = 0; r < 4; ++r) {
      int i = wv * 16 + quad * 4 + r;
      int j = nt * 16 + l15;
      float m = 0.f;
      if (j < i) m = kk[nt][r] * betas[i] * expf(fminf(gc[i] - gc[j], 0.f));
      MT[i][j] = m;
    }
  __syncthreads();

  if (wv == 0) {
    if (lane == 0) MT[0][0] = 1.f;
    for (int ii = 1; ii < 64; ++ii) {
      float s = 0.f;
      for (int l = 0; l < ii; ++l) s += MT[ii][l] * MT[l][lane];
      MT[ii][lane] = ((lane == ii) ? 1.f : 0.f) - s;
    }
  }
  {
    int band = (wv == 0) ? 3 : (wv - 1);
    floatx4 at[4];
#pragma unroll
    for (int nt = 0; nt < 4; ++nt) at[nt] = (floatx4){0.f, 0.f, 0.f, 0.f};
#pragma unroll
    for (int ks = 0; ks < 4; ++ks) {
      bf16x8 afr = *(const bf16x8*)&qn[((size_t)(t0 + band * 16 + l15) * NH_K + hk) * D_K + ks * 32 + quad * 8];
#pragma unroll
      for (int nt = 0; nt < 4; ++nt) {
        bf16x8 bfr = *(const bf16x8*)&kn[((size_t)(t0 + nt * 16 + l15) * NH_K + hk) * D_K + ks * 32 + quad * 8];
        at[nt] = __builtin_amdgcn_mfma_f32_16x16x32_bf16(afr, bfr, at[nt], 0, 0, 0);
      }
    }
    size_t abase = ((size_t)hv * 64 + n) * (64 * 64);
#pragma unroll
    for (int nt = 0; nt < 4; ++nt)
#pragma unroll
      for (int r = 0; r < 4; ++r) {
        int i = band * 16 + quad * 4 + r;
        int j = nt * 16 + l15;
        float dec = expf(fminf(gc[i] - gc[j], 0.f));
        float a = (j <= i) ? clampf(at[nt][r] * dec, 1e6f) : 0.f;
        attn[abase + (size_t)i * 64 + j] = (__bf16)a;
      }
  }
  __syncthreads();

  floatx4 ua[8], wa[8];
#pragma unroll
  for (int t = 0; t < 8; ++t) {
    ua[t] = (floatx4){0.f, 0.f, 0.f, 0.f};
    wa[t] = (floatx4){0.f, 0.f, 0.f, 0.f};
  }
#pragma unroll
  for (int ks = 0; ks < 2; ++ks) {
    bf16x8 uh, ul, wh, wl;
#pragma unroll
    for (int j = 0; j < 8; ++j) {
      int c = ks * 32 + quad * 8 + j;
      float raw = MT[wv * 16 + l15][c];
      float tu = raw * scu[c];
      float tw = raw * scw[c];
      __bf16 h1 = (__bf16)tu; uh[j] = h1; ul[j] = (__bf16)(tu - (float)h1);
      __bf16 h2 = (__bf16)tw; wh[j] = h2; wl[j] = (__bf16)(tw - (float)h2);
    }
#pragma unroll
    for (int nt = 0; nt < 8; ++nt) {
      bf16x8 vb = *(const bf16x8*)&vT[nt * 16 + l15][ks * 32 + quad * 8];
      ua[nt] = __builtin_amdgcn_mfma_f32_16x16x32_bf16(uh, vb, ua[nt], 0, 0, 0);
      ua[nt] = __builtin_amdgcn_mfma_f32_16x16x32_bf16(ul, vb, ua[nt], 0, 0, 0);
      bf16x8 kb = *(const bf16x8*)&kT[nt * 16 + l15][ks * 32 + quad * 8];
      wa[nt] = __builtin_amdgcn_mfma_f32_16x16x32_bf16(wh, kb, wa[nt], 0, 0, 0);
      wa[nt] = __builtin_amdgcn_mfma_f32_16x16x32_bf16(wl, kb, wa[nt], 0, 0, 0);
    }
  }
  size_t base = ((size_t)hv * 64 + n) * (64 * 128);
#pragma unroll
  for (int nt = 0; nt < 8; ++nt)
#pragma unroll
    for (int r = 0; r < 4; ++r) {
      int row = wv * 16 + quad * 4 + r;
      int dv  = nt * 16 + l15;
      u[base + (size_t)row * 128 + dv] = (__bf16)clampf(ua[nt][r], 1e6f);
      w[base + (size_t)row * 128 + dv] = (__bf16)clampf(wa[nt][r], 1e6f);
    }
}

// ---------------------------------------------------------------------------
// Sequential inter-chunk scan — 4-wave dk-split MFMA version.
// Grid = 8 dv-bands x 32 heads; 256 threads = 4 waves. Wave wv owns dk-slice
// [wv*32, wv*32+32): its S accumulators, sb columns, and kt rows are
// WAVE-PRIVATE (zero sync). Only the dk-contractions (m1: w@S, m3: q@S)
// cross slices: each wave computes partials for all 4 t-tiles, dumps to LDS,
// and after barrier A wave wv reduces its own t-tile (+u, x e^g) and writes
// its vt columns; after barrier B all waves run m3b/m4 on private slices.
// 2 barriers/chunk; 22 MFMA/wave/chunk; 4 SIMDs/CU active (was 1).
// ---------------------------------------------------------------------------
__global__ __launch_bounds__(256, 1) void scan_kernel(
    const __bf16* __restrict__ u, const __bf16* __restrict__ w, const __bf16* __restrict__ attn,
    const __bf16* __restrict__ qn, const __bf16* __restrict__ kn, const float* __restrict__ gcs,
    __bf16* __restrict__ obuf)
{
  __shared__ __bf16 sb_hi[16][136];   // S^T hi: [dv][dk]; wave-private columns
  __shared__ __bf16 sb_lo[16][136];
  __shared__ __bf16 vt[16][72];       // v_new^T [dv][t]; wave wv writes t-tile wv
  __shared__ __bf16 kt[128][72];      // k^T [dk][t]; wave-private rows
  __shared__ float redv[4][4][64][4]; // [writer wv][t-tile][lane][r] m1 partials
  __shared__ float redo[4][4][64][4]; // m3 partials

  const int hv   = blockIdx.x & 31;   // XCD = blockIdx%8 = hv%8 -> bands colocate
  const int band = blockIdx.x >> 5;
  const int dv0  = band * 16;
  const int hk   = hv >> 1;
  const int tid  = threadIdx.x;
  const int wv   = tid >> 6;          // dk-slice owner (ks index)
  const int lane = tid & 63;
  const int l15  = lane & 15;
  const int quad = lane >> 4;

  floatx4 S[2];                       // dk rows m = 2wv, 2wv+1 (own slice)
  S[0] = (floatx4){0.f, 0.f, 0.f, 0.f};
  S[1] = (floatx4){0.f, 0.f, 0.f, 0.f};
  for (int i = tid; i < 16 * 136 / 2; i += 256) {
    ((unsigned int*)sb_hi)[i] = 0u;
    ((unsigned int*)sb_lo)[i] = 0u;
  }
  __syncthreads();

  for (int n = 0; n < 64; ++n) {
    const int t0 = n * 64;
    const size_t cb = (size_t)hv * 64 + n;
    const float* gr = gcs + cb * 64;
    const size_t ub = cb * 8192;

    // ---- early loads: k rows (own dk-slice, lane owns t=lane) + u own tile ----
    const __bf16* krow = &kn[((size_t)(t0 + lane) * NH_K + hk) * D_K + wv * 32];
    bf16x8 kr[4];
#pragma unroll
    for (int c2 = 0; c2 < 4; ++c2) kr[c2] = *(const bf16x8*)&krow[c2 * 8];
    float uin[4];
#pragma unroll
    for (int r = 0; r < 4; ++r)
      uin[r] = (float)u[ub + (size_t)(wv * 16 + quad * 4 + r) * 128 + dv0 + l15];

    // ---- own S slice fragments (B: n=l15 dv, k=quad*8+j within slice) ----
    bf16x8 sh = *(const bf16x8*)&sb_hi[l15][wv * 32 + quad * 8];
    bf16x8 sl = *(const bf16x8*)&sb_lo[l15][wv * 32 + quad * 8];

    // ---- m1 partial: (-w[:, slice]) @ S_slice for all 4 t-tiles ----
    floatx4 av[4], ap[4];
#pragma unroll
    for (int mt = 0; mt < 4; ++mt) {
      av[mt] = (floatx4){0.f, 0.f, 0.f, 0.f};
      ap[mt] = (floatx4){0.f, 0.f, 0.f, 0.f};
    }
#pragma unroll
    for (int mt = 0; mt < 4; ++mt) {
      uint32x4 wu = *(const uint32x4*)&w[ub + (size_t)(mt * 16 + l15) * 128 + wv * 32 + quad * 8];
      wu[0] ^= 0x80008000u; wu[1] ^= 0x80008000u;
      wu[2] ^= 0x80008000u; wu[3] ^= 0x80008000u;
      bf16x8 wf = __builtin_bit_cast(bf16x8, wu);
      av[mt] = __builtin_amdgcn_mfma_f32_16x16x32_bf16(wf, sh, av[mt], 0, 0, 0);
      av[mt] = __builtin_amdgcn_mfma_f32_16x16x32_bf16(wf, sl, av[mt], 0, 0, 0);
    }
    // ---- m3 partial: q[:, slice] @ S_slice ----
#pragma unroll
    for (int mt = 0; mt < 4; ++mt) {
      bf16x8 qf = *(const bf16x8*)&qn[((size_t)(t0 + mt * 16 + l15) * NH_K + hk) * D_K + wv * 32 + quad * 8];
      ap[mt] = __builtin_amdgcn_mfma_f32_16x16x32_bf16(qf, sh, ap[mt], 0, 0, 0);
      ap[mt] = __builtin_amdgcn_mfma_f32_16x16x32_bf16(qf, sl, ap[mt], 0, 0, 0);
    }
    // ---- dump partials; stage own kt rows (wave-private) ----
#pragma unroll
    for (int mt = 0; mt < 4; ++mt) {
      *(floatx4*)&redv[wv][mt][lane][0] = av[mt];
      *(floatx4*)&redo[wv][mt][lane][0] = ap[mt];
    }
#pragma unroll
    for (int c2 = 0; c2 < 4; ++c2)
#pragma unroll
      for (int j = 0; j < 8; ++j)
        kt[wv * 32 + c2 * 8 + j][lane] = kr[c2][j];
    __syncthreads();                  // A: partials visible

    // ---- reduce own t-tile (mt = wv): v_new = u + sum, o = e^g * sum(qS) ----
    const float gl  = gr[63];
    const float egl = expf(gl);
    floatx4 vsum, osum;
#pragma unroll
    for (int r = 0; r < 4; ++r) { vsum[r] = uin[r]; osum[r] = 0.f; }
#pragma unroll
    for (int j = 0; j < 4; ++j) {
      floatx4 pv = *(const floatx4*)&redv[j][wv][lane][0];
      floatx4 po = *(const floatx4*)&redo[j][wv][lane][0];
#pragma unroll
      for (int r = 0; r < 4; ++r) { vsum[r] += pv[r]; osum[r] += po[r]; }
    }
#pragma unroll
    for (int r = 0; r < 4; ++r)
      osum[r] *= expf(gr[wv * 16 + quad * 4 + r]);
    {
      bf16x4 h4;
#pragma unroll
      for (int r = 0; r < 4; ++r) h4[r] = (__bf16)clampf(vsum[r], 1e8f);
      *(bf16x4*)&vt[l15][wv * 16 + quad * 4] = h4;
    }
    __syncthreads();                  // B: vt complete

    // ---- full v_new fragments ----
    bf16x8 vf0 = *(const bf16x8*)&vt[l15][quad * 8];
    bf16x8 vf1 = *(const bf16x8*)&vt[l15][32 + quad * 8];

    // ---- m3b: o(own t-tile) += attn @ v_new ----
    {
      bf16x8 a0 = *(const bf16x8*)&attn[cb * 4096 + (size_t)(wv * 16 + l15) * 64 + quad * 8];
      bf16x8 a1 = *(const bf16x8*)&attn[cb * 4096 + (size_t)(wv * 16 + l15) * 64 + 32 + quad * 8];
      osum = __builtin_amdgcn_mfma_f32_16x16x32_bf16(a0, vf0, osum, 0, 0, 0);
      osum = __builtin_amdgcn_mfma_f32_16x16x32_bf16(a1, vf1, osum, 0, 0, 0);
    }
#pragma unroll
    for (int r = 0; r < 4; ++r)
      obuf[((size_t)(t0 + wv * 16 + quad * 4 + r) * NH_V + hv) * D_V + dv0 + l15]
          = (__bf16)clampf(osum[r], 1e8f);

    // ---- m4: S_slice = e^gl * S_slice + k^T_slice @ (v_new * e^(gl-g)) ----
    float ek0[8], ek1[8];
#pragma unroll
    for (int j = 0; j < 8; ++j) {
      ek0[j] = expf(fminf(gl - gr[quad * 8 + j], 0.f));
      ek1[j] = expf(fminf(gl - gr[32 + quad * 8 + j], 0.f));
    }
    bf16x8 vfd0, vfd1;
#pragma unroll
    for (int j = 0; j < 8; ++j) {
      vfd0[j] = (__bf16)((float)vf0[j] * ek0[j]);
      vfd1[j] = (__bf16)((float)vf1[j] * ek1[j]);
    }
#pragma unroll
    for (int m2 = 0; m2 < 2; ++m2) {
      const int m = wv * 2 + m2;
#pragma unroll
      for (int r = 0; r < 4; ++r) S[m2][r] *= egl;
      bf16x8 kf0 = *(const bf16x8*)&kt[m * 16 + l15][quad * 8];
      bf16x8 kf1 = *(const bf16x8*)&kt[m * 16 + l15][32 + quad * 8];
      S[m2] = __builtin_amdgcn_mfma_f32_16x16x32_bf16(kf0, vfd0, S[m2], 0, 0, 0);
      S[m2] = __builtin_amdgcn_mfma_f32_16x16x32_bf16(kf1, vfd1, S[m2], 0, 0, 0);
      // clamp + dump hi/lo (own columns)
      bf16x4 h4, l4;
#pragma unroll
      for (int r = 0; r < 4; ++r) {
        float v = clampf(S[m2][r], 1e8f);
        S[m2][r] = v;
        __bf16 h = (__bf16)v;
        h4[r] = h;
        l4[r] = (__bf16)(v - (float)h);
      }
      *(bf16x4*)&sb_hi[l15][m * 16 + quad * 4] = h4;
      *(bf16x4*)&sb_lo[l15][m * 16 + quad * 4] = l4;
    }
  }
}

// ---------------------------------------------------------------------------
// Gated RMS norm: wave per (t,hv) row, bf16x2 loads, shfl reduce, 0 barriers.
// ---------------------------------------------------------------------------
__global__ __launch_bounds__(256) void gate_kernel(
    const __bf16* __restrict__ obuf, const __bf16* __restrict__ qkvz,
    const void* __restrict__ norm_w, __bf16* __restrict__ og,
    const int* __restrict__ flagp)
{
  const bool f32 = (*flagp != 0);
  const int t = blockIdx.x;
  const int wv = threadIdx.x >> 6, lane = threadIdx.x & 63;
  const int hv = blockIdx.y * 4 + wv;
  const int d = lane * 2;
  bf16x2 ov = *(const bf16x2*)&obuf[((size_t)t * NH_V + hv) * D_V + d];
  bf16x2 zv = *(const bf16x2*)&qkvz[(size_t)t * QKVZ_COLS + (hv >> 1) * 768 + 512 + (hv & 1) * 128 + d];
  float z0 = (float)zv[0], z1 = (float)zv[1];
  float v0 = (float)ov[0] * (z0 * sigm(z0));
  float v1 = (float)ov[1] * (z1 * sigm(z1));
  float ss = v0 * v0 + v1 * v1;
#pragma unroll
  for (int off = 32; off; off >>= 1) ss += __shfl_xor(ss, off, 64);
  float scl = rsqrtf(ss * (1.f / 128.f) + 1e-6f);
  bf16x2 o;
  o[0] = (__bf16)(v0 * scl * loadF(norm_w, d, f32));
  o[1] = (__bf16)(v1 * scl * loadF(norm_w, d + 1, f32));
  *(bf16x2*)&og[(size_t)t * 4096 + hv * 128 + d] = o;
}

// ---------------------------------------------------------------------------
extern "C" void kernel_launch(void* const* d_in, const int* in_sizes, int n_in,
                              void* d_out, int out_size, void* d_ws, size_t ws_size,
                              hipStream_t stream) {
  (void)in_sizes; (void)n_in; (void)out_size;
  const void* x     = d_in[0];
  const void* Wqkvz = d_in[3];
  const void* Wba   = d_in[4];
  const void* convw = d_in[5];
  const void* dtb   = d_in[6];
  const void* Alog  = d_in[7];
  const void* normw = d_in[8];
  const void* Wout  = d_in[9];

  char* ws = (char*)d_ws;
  size_t off = 0;
  int*    flag = (int*)(ws + off);    off += 256;
  __bf16* qkvz = (__bf16*)(ws + off); off += (size_t)4096 * 12288 * 2;
  float* ba    = (float*)(ws + off);  off += (size_t)4096 * 64 * 4;
  float* gbuf  = (float*)(ws + off);  off += (size_t)4096 * 32 * 4;
  float* betab = (float*)(ws + off);  off += (size_t)4096 * 32 * 4;
  float* gcs   = (float*)(ws + off);  off += (size_t)32 * 64 * 64 * 4;
  __bf16* qn   = (__bf16*)(ws + off); off += (size_t)4096 * 2048 * 2;
  __bf16* kn   = (__bf16*)(ws + off); off += (size_t)4096 * 2048 * 2;
  __bf16* vv   = (__bf16*)(ws + off); off += (size_t)4096 * 4096 * 2;
  __bf16* ubuf = (__bf16*)(ws + off); off += (size_t)32 * 64 * 8192 * 2;
  __bf16* wbuf = (__bf16*)(ws + off); off += (size_t)32 * 64 * 8192 * 2;
  __bf16* attn = (__bf16*)(ws + off); off += (size_t)32 * 64 * 4096 * 2;
  __bf16* obuf = vv;      // overlay: vv dead after prep
  __bf16* og   = ubuf;    // overlay: ubuf dead after scan
  __bf16* WqkvzT = ubuf;  // 12288x2048 bf16 <= ubuf+wbuf; dead before prep
  __bf16* xb     = attn;  // 4096x2048 bf16 = attn size; dead before prep
  __bf16* WoutT  = wbuf;  // 2048x4096 bf16 <= wbuf; written after scan
  if (ws_size < off) return;

  detect_kernel<<<1, 256, 0, stream>>>((const unsigned int*)x, flag);
  convx_kernel<<<4096, 256, 0, stream>>>(x, xb, flag);
  trans_kernel<<<dim3(64, 384), 256, 0, stream>>>(Wqkvz, WqkvzT, 2048, 12288, flag);
  gemm_bt2<false><<<dim3(48, 16), 512, 0, stream>>>(xb, WqkvzT, qkvz, 4096, 12288, 2048);
  ba_kernel<<<4096, 64, 0, stream>>>(x, Wba, ba, flag);
  conv_kernel<<<dim3(64, 16), 256, 0, stream>>>(qkvz, convw, qn, kn, vv, flag);
  gb_kernel<<<4096, 64, 0, stream>>>(ba, dtb, Alog, gbuf, betab, flag);
  prep_kernel<<<2048, 256, 0, stream>>>(qn, kn, vv, gbuf, betab, gcs, ubuf, wbuf, attn);
  scan_kernel<<<256, 256, 0, stream>>>(ubuf, wbuf, attn, qn, kn, gcs, obuf);
  gate_kernel<<<dim3(4096, 8), 256, 0, stream>>>(obuf, qkvz, normw, og, flag);
  trans_kernel<<<dim3(128, 64), 256, 0, stream>>>(Wout, WoutT, 4096, 2048, flag);
  gemm_bt<true><<<dim3(16, 32), 256, 0, stream>>>(og, WoutT, d_out, 4096, 2048, 4096);
}